// Round 7
// baseline (5269.302 us; speedup 1.0000x reference)
//
#include <hip/hip_runtime.h>

#define L 432
#define DM 64
#define NB 512
#define TSROWS 146   // rows {287..431} -> 0..144, row 0 -> 145
#define TSSTR  (TSROWS*DM)

// ---------------- diagnostic: encode ws_size (MB) into absmax if workspace too small ----------------
__global__ void af_wsdiag(float* __restrict__ out, float val){
  if (threadIdx.x==0) out[0]=val;
}

// ---------------- weight prep: conv transposes, ff2T, fused attn matrices ----------------
// M2[a*64+b]  = sum_o Wq[o,b]*Wk[o,a]      (q.k Gram fold; q/k biases provably cancel in topk+softmax)
// PM[a*64+o]  = sum_d Wo[o,d]*Wv[d,a]      (agg->vproj->oproj fold; uses sum_k w_k == 1)
// cvec[o]     = sum_d bv[d]*Wo[o,d] + bo[o]
__global__ void af_wprep(const float* __restrict__ c0w, const float* __restrict__ c1w,
                         const float* __restrict__ c2w, const float* __restrict__ ff2,
                         const float* __restrict__ sawq, const float* __restrict__ sawk,
                         const float* __restrict__ sawv, const float* __restrict__ sawo,
                         const float* __restrict__ sabv, const float* __restrict__ sabo,
                         const float* __restrict__ cawq, const float* __restrict__ cawk,
                         const float* __restrict__ cawv, const float* __restrict__ cawo,
                         const float* __restrict__ cabv, const float* __restrict__ cabo,
                         float* __restrict__ w0T, float* __restrict__ w1T,
                         float* __restrict__ w2T, float* __restrict__ ff2T,
                         float* __restrict__ M2sa, float* __restrict__ M2ca,
                         float* __restrict__ PMsa, float* __restrict__ PMca,
                         float* __restrict__ csa, float* __restrict__ cca){
  int stride = gridDim.x*blockDim.x;
  int tid = blockIdx.x*blockDim.x + threadIdx.x;
  for (int i=tid;i<1344;i+=stride){ int o=i&63, r=i>>6; int c=r/7, kh=r%7; w0T[i]=c0w[o*21+c*7+kh]; }
  for (int i=tid;i<12288;i+=stride){ int o=i&63, r=i>>6; int c=r>>6, rem=r&63, kh=rem>>5, kw=rem&31;
                                     w1T[i]=c1w[o*192+c*64+kh*32+kw]; }
  for (int i=tid;i<9216;i+=stride){ int o=i&63, r=i>>6; int c=r/48, kw=r%48; w2T[i]=c2w[o*144+c*48+kw]; }
  for (int i=tid;i<8192;i+=stride){ int o=i&63, j=i>>6; ff2T[i]=ff2[o*128+j]; }
  for (int i=tid;i<4096;i+=stride){
    int a=i>>6, b=i&63;
    float s1=0.f,s2=0.f,s3=0.f,s4=0.f;
    for (int o=0;o<64;o++){
      s1 = fmaf(sawk[o*64+a], sawq[o*64+b], s1);
      s2 = fmaf(cawk[o*64+a], cawq[o*64+b], s2);
      s3 = fmaf(sawo[b*64+o], sawv[o*64+a], s3);
      s4 = fmaf(cawo[b*64+o], cawv[o*64+a], s4);
    }
    M2sa[i]=s1; M2ca[i]=s2; PMsa[i]=s3; PMca[i]=s4;
  }
  for (int i=tid;i<64;i+=stride){
    float s1=sabo[i], s2=cabo[i];
    for (int d=0;d<64;d++){ s1=fmaf(sabv[d], sawo[i*64+d], s1); s2=fmaf(cabv[d], cawo[i*64+d], s2); }
    csa[i]=s1; cca[i]=s2;
  }
}

// ---------------- conv stems: x = day_seq viewed as [b][c][h(7)][w(144)] ----------------
// x[b,c,hh,w] = ds[b*3024 + hh*432 + w*3 + c]
__global__ __launch_bounds__(256) void af_conv1(const float* __restrict__ ds, const float* __restrict__ w0T,
                          const float* __restrict__ b0, float* __restrict__ out){
  int b = blockIdx.x;
  int wv = threadIdx.x>>6, lane = threadIdx.x&63;
  const float* xb = ds + (size_t)b*3024;
  for (int it=0; it<2; it++){
    int tl = it*64+lane; bool ok = tl<108;
    int t = wv*108 + (ok?tl:0);
    int h = t/144, w = t - h*144;
    for (int oc=0; oc<4; oc++){
      float acc[16];
      #pragma unroll
      for (int u=0;u<16;u++) acc[u]=b0[oc*16+u];
      for (int kh=0; kh<7; kh++){
        int hh = h+kh-1;
        bool val = (hh>=0)&&(hh<7);
        int hc = val?hh:0;
        #pragma unroll
        for (int c=0;c<3;c++){
          float xv = xb[hc*432 + w*3 + c];
          xv = val?xv:0.f;
          const float* wr = w0T + (c*7+kh)*64 + oc*16;
          #pragma unroll
          for (int u=0;u<16;u++) acc[u]=fmaf(xv,wr[u],acc[u]);
        }
      }
      if (ok){
        float* op = out + ((size_t)b*L + t)*DM + oc*16;
        #pragma unroll
        for (int q=0;q<4;q++)
          *reinterpret_cast<float4*>(op+q*4)=make_float4(acc[q*4],acc[q*4+1],acc[q*4+2],acc[q*4+3]);
      }
    }
  }
}

__global__ __launch_bounds__(256) void af_conv2(const float* __restrict__ ds, const float* __restrict__ w1T,
                          const float* __restrict__ b1, float* __restrict__ out){
  int b = blockIdx.x;
  int wv = threadIdx.x>>6, lane = threadIdx.x&63;
  const float* xb = ds + (size_t)b*3024;
  for (int it=0; it<2; it++){
    int tl = it*64+lane; bool ok = tl<108;
    int t = wv*108 + (ok?tl:0);
    int f = t + 224;           // 8*82=656 outputs, keep last 432
    int h = f/82, w = f - h*82;
    for (int oc=0; oc<4; oc++){
      float acc[16];
      #pragma unroll
      for (int u=0;u<16;u++) acc[u]=b1[oc*16+u];
      #pragma unroll
      for (int kh=0; kh<2; kh++){
        int hh = h+kh-1;       // h in [2,7] -> hh in [1,7]
        bool val = hh<7;
        int hc = val?hh:0;
        for (int kw=0; kw<32; kw++){
          #pragma unroll
          for (int c=0;c<3;c++){
            float xv = xb[hc*432 + (w+2*kw)*3 + c];
            xv = val?xv:0.f;
            const float* wr = w1T + ((c*2+kh)*32+kw)*64 + oc*16;
            #pragma unroll
            for (int u=0;u<16;u++) acc[u]=fmaf(xv,wr[u],acc[u]);
          }
        }
      }
      if (ok){
        float* op = out + ((size_t)b*L + t)*DM + oc*16;
        #pragma unroll
        for (int q=0;q<4;q++)
          *reinterpret_cast<float4*>(op+q*4)=make_float4(acc[q*4],acc[q*4+1],acc[q*4+2],acc[q*4+3]);
      }
    }
  }
}

// conv3 (trend stem): only sum_d s3[t,d]*pw[d] for t in [288,432) is ever used.
__global__ __launch_bounds__(256) void af_conv3td(const float* __restrict__ ds, const float* __restrict__ w2T,
                          const float* __restrict__ b2, const float* __restrict__ pw,
                          float* __restrict__ td){
  int b = blockIdx.x;
  int tid = threadIdx.x;
  if (tid>=144) return;
  const float* xb = ds + (size_t)b*3024;
  int t = 288+tid;
  int f = t + 247;             // 7*97=679 outputs, keep last 432
  int h = f/97, w = f - h*97;  // h in [5,6], always valid
  float tdv=0.f;
  for (int oc=0; oc<4; oc++){
    float acc[16];
    #pragma unroll
    for (int u=0;u<16;u++) acc[u]=b2[oc*16+u];
    for (int kw=0; kw<48; kw++){
      #pragma unroll
      for (int c=0;c<3;c++){
        float xv = xb[h*432 + (w+kw)*3 + c];
        const float* wr = w2T + (c*48+kw)*64 + oc*16;
        #pragma unroll
        for (int u=0;u<16;u++) acc[u]=fmaf(xv,wr[u],acc[u]);
      }
    }
    #pragma unroll
    for (int u=0;u<16;u++) tdv = fmaf(acc[u], pw[oc*16+u], tdv);
  }
  td[b*144 + tid] = tdv;
}

// ---------------- u = src @ M2 (64x64, row-major [a][b]) ----------------
__global__ __launch_bounds__(256) void af_lin(const float* __restrict__ src,
      const float* __restrict__ M2, float* __restrict__ dst){
  int b = blockIdx.y;
  int t = blockIdx.x*256 + threadIdx.x;
  if (t>=L) return;
  float xr[64];
  const float4* xp = reinterpret_cast<const float4*>(src + ((size_t)b*L+t)*DM);
  #pragma unroll
  for (int i=0;i<16;i++){ float4 v=xp[i]; xr[4*i]=v.x; xr[4*i+1]=v.y; xr[4*i+2]=v.z; xr[4*i+3]=v.w; }
  float acc[64];
  #pragma unroll
  for (int o=0;o<64;o++) acc[o]=0.f;
  for (int a=0;a<64;a++){
    float x = xr[a];
    const float* mr = M2 + a*64;
    #pragma unroll
    for (int o=0;o<64;o++) acc[o]=fmaf(x, mr[o], acc[o]);
  }
  float* orow = dst + ((size_t)b*L+t)*DM;
  #pragma unroll
  for (int q=0;q<16;q++)
    *reinterpret_cast<float4*>(orow+q*4)=make_float4(acc[q*4],acc[q*4+1],acc[q*4+2],acc[q*4+3]);
}

// ---------------- circular correlation: mv[b,tau] = (1/64) sum_t X[b,t,:].Y[b,(t+tau)%L,:] ----------------
__global__ __launch_bounds__(256) void af_corr(const float* __restrict__ X, const float* __restrict__ Y,
                                               float* __restrict__ mv){
  int b = blockIdx.x;
  int tid = threadIdx.x;
  int wv = tid>>6, lane = tid&63;
  int tau0 = lane*8;
  bool act = lane < 54;           // 54*8 = 432 taus
  const float* Xb = X + (size_t)b*L*DM;
  const float* Yb = Y + (size_t)b*L*DM;
  float acc[8];
  #pragma unroll
  for (int a=0;a<8;a++) acc[a]=0.f;
  for (int dq=0; dq<4; dq++){
    int d0 = wv*16 + dq*4;
    for (int t0=0; t0<L; t0+=16){
      float4 xq[16];
      #pragma unroll
      for (int i=0;i<16;i++)
        xq[i] = *reinterpret_cast<const float4*>(Xb + (t0+i)*DM + d0);  // wave-uniform
      float4 kr[8];
      #pragma unroll
      for (int j=0;j<7;j++){
        int r = t0 + tau0 + j; if (r>=L) r-=L; if(!act) r=0;
        kr[j] = *reinterpret_cast<const float4*>(Yb + r*DM + d0);
      }
      #pragma unroll
      for (int i=0;i<16;i++){
        int r = t0 + tau0 + i + 7; if (r>=L) r-=L; if(!act) r=0;
        kr[(i+7)&7] = *reinterpret_cast<const float4*>(Yb + r*DM + d0);
        float4 xv = xq[i];
        #pragma unroll
        for (int a=0;a<8;a++){
          float4 kv = kr[(i+a)&7];
          acc[a]=fmaf(xv.x,kv.x,acc[a]); acc[a]=fmaf(xv.y,kv.y,acc[a]);
          acc[a]=fmaf(xv.z,kv.z,acc[a]); acc[a]=fmaf(xv.w,kv.w,acc[a]);
        }
      }
    }
  }
  __shared__ float red[4][L];
  if (act){
    #pragma unroll
    for (int a=0;a<8;a++) red[wv][tau0+a]=acc[a];
  }
  __syncthreads();
  for (int t=tid; t<L; t+=256){
    float s = (red[0][t]+red[1][t]) + (red[2][t]+red[3][t]);
    mv[(size_t)b*L + t] = s * (1.f/64.f);
  }
}

// ---------------- batch-mean + top-4 lag selection ----------------
__global__ void af_topk(const float* __restrict__ mv, int* __restrict__ idx){
  __shared__ float gm[L];
  int tid = threadIdx.x;
  for (int t=tid; t<L; t+=256){
    float s=0.f;
    for (int b=0;b<NB;b++) s += mv[(size_t)b*L + t];
    gm[t]=s;
  }
  __syncthreads();
  if (tid==0){
    for (int p=0;p<4;p++){
      float best=-1e30f; int bi=0;
      for (int t=0;t<L;t++){ float v=gm[t]; if (v>best){best=v;bi=t;} }
      idx[p]=bi; gm[bi]=-1e30f;
    }
  }
}

// ---------------- out[t] = resid[t] + (sum_k w_k * vsrc[(t+idx_k)%L]) @ PM + cvec ----------------
__global__ __launch_bounds__(256) void af_agg2(const float* __restrict__ vsrc, const float* __restrict__ resid,
      const float* __restrict__ mv, const int* __restrict__ idx, const float* __restrict__ PM,
      const float* __restrict__ cvec, float* __restrict__ outp){
  int b = blockIdx.y;
  int t = blockIdx.x*256 + threadIdx.x;
  if (t>=L) return;
  int i0=idx[0],i1=idx[1],i2=idx[2],i3=idx[3];
  float w0=mv[(size_t)b*L+i0], w1=mv[(size_t)b*L+i1], w2=mv[(size_t)b*L+i2], w3=mv[(size_t)b*L+i3];
  float m = fmaxf(fmaxf(w0,w1),fmaxf(w2,w3));
  w0=expf(w0-m); w1=expf(w1-m); w2=expf(w2-m); w3=expf(w3-m);
  float inv = 1.f/(w0+w1+w2+w3);
  w0*=inv; w1*=inv; w2*=inv; w3*=inv;
  float aggx[64];
  #pragma unroll
  for (int d=0;d<64;d++) aggx[d]=0.f;
  int rr[4]={t+i0,t+i1,t+i2,t+i3};
  float ww[4]={w0,w1,w2,w3};
  #pragma unroll
  for (int k=0;k<4;k++){
    int r=rr[k]; if (r>=L) r-=L;
    const float4* vp = reinterpret_cast<const float4*>(vsrc + ((size_t)b*L+r)*DM);
    float wk=ww[k];
    #pragma unroll
    for (int i=0;i<16;i++){
      float4 q=vp[i];
      aggx[4*i]  =fmaf(wk,q.x,aggx[4*i]);   aggx[4*i+1]=fmaf(wk,q.y,aggx[4*i+1]);
      aggx[4*i+2]=fmaf(wk,q.z,aggx[4*i+2]); aggx[4*i+3]=fmaf(wk,q.w,aggx[4*i+3]);
    }
  }
  float acc[64];
  #pragma unroll
  for (int o=0;o<64;o++) acc[o]=cvec[o];
  for (int a=0;a<64;a++){
    float x = aggx[a];
    const float* pr = PM + a*64;
    #pragma unroll
    for (int o=0;o<64;o++) acc[o]=fmaf(x, pr[o], acc[o]);
  }
  const float* rrow = resid + ((size_t)b*L+t)*DM;
  float* orow = outp + ((size_t)b*L+t)*DM;
  #pragma unroll
  for (int q=0;q<16;q++){
    float4 rv = *reinterpret_cast<const float4*>(rrow+q*4);
    *reinterpret_cast<float4*>(orow+q*4)=make_float4(rv.x+acc[q*4],rv.y+acc[q*4+1],
                                                     rv.z+acc[q*4+2],rv.w+acc[q*4+3]);
  }
}

// ---------------- series_decomp: xo = x - ma25(x); ts (+)= ma25(x) for rows {0,287..431} only ----------------
__global__ void af_decomp2(const float* __restrict__ x, float* __restrict__ xo,
                           float* __restrict__ ts, int accum){
  int g = blockIdx.x*256 + threadIdx.x;
  int b = g>>8, chunk=(g>>6)&3, d=g&63;
  const float* xb = x + (size_t)b*L*DM + d;
  float* tsb = ts + (size_t)b*TSSTR + d;
  int t0 = chunk*108;
  float s = 0.f;
  for (int j=t0-12; j<=t0+12; j++){
    int jc = j<0?0:(j>L-1?L-1:j);
    s += xb[jc*DM];
  }
  for (int t=t0; t<t0+108; t++){
    float mean = s*(1.f/25.f);
    xo[(size_t)b*L*DM + t*DM + d] = xb[t*DM] - mean;
    int ridx = (t>=287) ? (t-287) : (t==0 ? 145 : -1);
    if (ridx>=0){
      float* tp = tsb + ridx*64;
      *tp = accum ? (*tp + mean) : mean;
    }
    int ja=t+13; ja = ja>L-1?L-1:ja;
    int jr=t-12; jr = jr<0?0:jr;
    s += xb[ja*DM] - xb[jr*DM];
  }
}

// ---------------- FFN: out = x + gelu(x@ff1.T)@ff2.T ----------------
__global__ __launch_bounds__(256) void af_ff(const float* __restrict__ x, const float* __restrict__ ff1,
      const float* __restrict__ ff2T, float* __restrict__ out){
  int b=blockIdx.y; int t=blockIdx.x*256+threadIdx.x;
  if (t>=L) return;
  float xr[64];
  const float4* xp = reinterpret_cast<const float4*>(x + ((size_t)b*L+t)*DM);
  #pragma unroll
  for (int i=0;i<16;i++){ float4 v=xp[i]; xr[4*i]=v.x; xr[4*i+1]=v.y; xr[4*i+2]=v.z; xr[4*i+3]=v.w; }
  float acc[64];
  #pragma unroll
  for (int o=0;o<64;o++) acc[o]=0.f;
  for (int j=0;j<128;j++){
    const float* w1r = ff1 + j*64;
    float h=0.f;
    #pragma unroll
    for (int d=0;d<64;d++) h=fmaf(xr[d],w1r[d],h);
    h = 0.5f*h*(1.f + erff(h*0.70710678118654752440f));
    const float* w2r = ff2T + j*64;
    #pragma unroll
    for (int o=0;o<64;o++) acc[o]=fmaf(h,w2r[o],acc[o]);
  }
  float* orow = out + ((size_t)b*L+t)*DM;
  #pragma unroll
  for (int q=0;q<16;q++)
    *reinterpret_cast<float4*>(orow+q*4)=make_float4(xr[q*4]+acc[q*4],xr[q*4+1]+acc[q*4+1],
                                                     xr[q*4+2]+acc[q*4+2],xr[q*4+3]+acc[q*4+3]);
}

// ---------------- final: layernorm (+ time-mean fold) + trend scalars + circ-conv trend head ----------------
__global__ __launch_bounds__(256) void af_final2(const float* __restrict__ xd, const float* __restrict__ td,
    const float* __restrict__ ts, const float* __restrict__ lng, const float* __restrict__ lnb,
    const float* __restrict__ projw, const float* __restrict__ pw, const float* __restrict__ pb,
    float* __restrict__ outp){
  int b = blockIdx.x; int tid = threadIdx.x;
  __shared__ float sv[L];
  __shared__ float cshared;
  for (int l=tid; l<L; l+=256){
    const float4* xp = reinterpret_cast<const float4*>(xd + ((size_t)b*L+l)*DM);
    float xr[64];
    #pragma unroll
    for (int i=0;i<16;i++){ float4 q=xp[i]; xr[4*i]=q.x; xr[4*i+1]=q.y; xr[4*i+2]=q.z; xr[4*i+3]=q.w; }
    float mu=0.f;
    #pragma unroll
    for (int d=0;d<64;d++) mu+=xr[d];
    mu *= (1.f/64.f);
    float var=0.f;
    #pragma unroll
    for (int d=0;d<64;d++){ float df=xr[d]-mu; var=fmaf(df,df,var); }
    var *= (1.f/64.f);
    float inv = 1.f/sqrtf(var+1e-5f);
    float s=0.f;
    #pragma unroll
    for (int d=0;d<64;d++) s += ((xr[d]-mu)*inv*lng[d] + lnb[d]) * pw[d];
    sv[l]=s;
  }
  __syncthreads();
  if (tid==0){
    float c=0.f;
    for (int l=0;l<L;l++) c+=sv[l];
    cshared = c*(1.f/432.f);
  }
  __syncthreads();
  float cv = cshared;
  int l = 288 + tid;
  if (l < L){
    const float* r0 = ts + (size_t)b*TSSTR + (l-288)*64;            // row l-1
    const float* r1 = r0 + 64;                                      // row l
    const float* r2 = (l==L-1) ? (ts + (size_t)b*TSSTR + 145*64)    // row 0 (wrap)
                               : (r1 + 64);                         // row l+1
    float rt=0.f;
    #pragma unroll
    for (int d=0;d<64;d++)
      rt += r0[d]*projw[d*3] + r1[d]*projw[d*3+1] + r2[d]*projw[d*3+2];
    float Ps=0.f;
    #pragma unroll
    for (int d=0;d<64;d++) Ps += pw[d];
    outp[b*144 + (l-288)] = sv[l] - cv + td[b*144 + (l-288)] + rt*Ps + pb[0];
  }
}

extern "C" void kernel_launch(void* const* d_in, const int* in_sizes, int n_in,
                              void* d_out, int out_size, void* d_ws, size_t ws_size,
                              hipStream_t stream) {
  const float* day  = (const float*)d_in[0];
  const float* c0w  = (const float*)d_in[1];
  const float* c0b  = (const float*)d_in[2];
  const float* c1w  = (const float*)d_in[3];
  const float* c1b  = (const float*)d_in[4];
  const float* c2w  = (const float*)d_in[5];
  const float* c2b  = (const float*)d_in[6];
  const float* sa_wq=(const float*)d_in[7];  const float* sa_bq=(const float*)d_in[8];
  const float* sa_wk=(const float*)d_in[9];  const float* sa_bk=(const float*)d_in[10];
  const float* sa_wv=(const float*)d_in[11]; const float* sa_bv=(const float*)d_in[12];
  const float* sa_wo=(const float*)d_in[13]; const float* sa_bo=(const float*)d_in[14];
  const float* ca_wq=(const float*)d_in[15]; const float* ca_bq=(const float*)d_in[16];
  const float* ca_wk=(const float*)d_in[17]; const float* ca_bk=(const float*)d_in[18];
  const float* ca_wv=(const float*)d_in[19]; const float* ca_bv=(const float*)d_in[20];
  const float* ca_wo=(const float*)d_in[21]; const float* ca_bo=(const float*)d_in[22];
  const float* ff1w = (const float*)d_in[23];
  const float* ff2w = (const float*)d_in[24];
  const float* projw= (const float*)d_in[25];
  const float* lng  = (const float*)d_in[26];
  const float* lnb  = (const float*)d_in[27];
  const float* predw= (const float*)d_in[28];
  const float* predb= (const float*)d_in[29];
  (void)sa_bq; (void)sa_bk; (void)ca_bq; (void)ca_bk;  // provably cancel in softmax/top-k
  float* out = (float*)d_out;

  const size_t SZ = (size_t)NB*L*DM;          // 14,155,776 floats per panel
  const size_t need = 3*SZ + (size_t)NB*TSSTR + (size_t)NB*144 + (size_t)NB*L + 16
                      + 1344 + 12288 + 9216 + 8192 + 4*4096 + 128;
  if (ws_size < need*sizeof(float)){
    // diagnostic: absmax will print ~ws_size in MB
    af_wsdiag<<<dim3(1), dim3(64), 0, stream>>>(out, (float)(ws_size>>20));
    return;
  }

  float* ws = (float*)d_ws;
  float* A  = ws;
  float* B  = A + SZ;
  float* C  = B + SZ;
  float* TS = C + SZ;                         // NB*146*64
  float* TD = TS + (size_t)NB*TSSTR;          // NB*144
  float* MV = TD + (size_t)NB*144;            // NB*L
  int*   IDXP = (int*)(MV + (size_t)NB*L);
  float* WT = MV + (size_t)NB*L + 16;
  float* w0T = WT;             // 1344
  float* w1T = w0T + 1344;     // 12288
  float* w2T = w1T + 12288;    // 9216
  float* ff2T= w2T + 9216;     // 8192
  float* M2sa= ff2T + 8192;    // 4096
  float* M2ca= M2sa + 4096;
  float* PMsa= M2ca + 4096;
  float* PMca= PMsa + 4096;
  float* csa = PMca + 4096;    // 64
  float* cca = csa + 64;       // 64

  dim3 blk(256);
  dim3 gridT(2, NB);

  af_wprep<<<dim3(48), blk, 0, stream>>>(c0w, c1w, c2w, ff2w,
      sa_wq, sa_wk, sa_wv, sa_wo, sa_bv, sa_bo,
      ca_wq, ca_wk, ca_wv, ca_wo, ca_bv, ca_bo,
      w0T, w1T, w2T, ff2T, M2sa, M2ca, PMsa, PMca, csa, cca);
  af_conv1 <<<dim3(NB), blk, 0, stream>>>(day, w0T, c0b, A);          // A = xd0
  af_conv2 <<<dim3(NB), blk, 0, stream>>>(day, w1T, c1b, B);          // B = cross
  af_conv3td<<<dim3(NB), blk, 0, stream>>>(day, w2T, c2b, predw, TD); // TD = trend . pw

  // ---- self attention ----
  af_lin <<<gridT, blk, 0, stream>>>(A, M2sa, C);                     // C = u
  af_corr<<<dim3(NB), blk, 0, stream>>>(C, A, MV);
  af_topk<<<dim3(1), blk, 0, stream>>>(MV, IDXP);
  af_agg2<<<gridT, blk, 0, stream>>>(A, A, MV, IDXP, PMsa, csa, C);   // C = xd1
  af_decomp2<<<dim3(NB), blk, 0, stream>>>(C, A, TS, 0);              // A = xd2, TS = t1

  // ---- cross attention ----
  af_lin <<<gridT, blk, 0, stream>>>(B, M2ca, C);                     // C = u (from cross)
  af_corr<<<dim3(NB), blk, 0, stream>>>(C, A, MV);
  af_topk<<<dim3(1), blk, 0, stream>>>(MV, IDXP);
  af_agg2<<<gridT, blk, 0, stream>>>(B, A, MV, IDXP, PMca, cca, C);   // C = xd3 (v from cross)
  af_decomp2<<<dim3(NB), blk, 0, stream>>>(C, A, TS, 1);              // A = xd4, TS += t2

  // ---- FFN ----
  af_ff<<<gridT, blk, 0, stream>>>(A, ff1w, ff2T, B);                 // B = xd4 + ffn
  af_decomp2<<<dim3(NB), blk, 0, stream>>>(B, A, TS, 1);              // A = xd5, TS += t3

  // ---- layernorm + trend + head ----
  af_final2<<<dim3(NB), blk, 0, stream>>>(A, TD, TS, lng, lnb, projw, predw, predb, out);
}

// Round 8
// 2003.148 us; speedup vs baseline: 2.6305x; 2.6305x over previous
//
#include <hip/hip_runtime.h>

#define L 432
#define DM 64
#define NB 512
#define TSROWS 146   // rows {287..431} -> 0..144, row 0 -> 145
#define TSSTR  (TSROWS*DM)

// ---------------- diagnostic: encode ws_size (MB) into absmax if workspace too small ----------------
__global__ void af_wsdiag(float* __restrict__ out, float val){
  if (threadIdx.x==0) out[0]=val;
}

// ---------------- weight prep: conv transposes, ff2T, fused attn matrices ----------------
__global__ void af_wprep(const float* __restrict__ c0w, const float* __restrict__ c1w,
                         const float* __restrict__ c2w, const float* __restrict__ ff2,
                         const float* __restrict__ sawq, const float* __restrict__ sawk,
                         const float* __restrict__ sawv, const float* __restrict__ sawo,
                         const float* __restrict__ sabv, const float* __restrict__ sabo,
                         const float* __restrict__ cawq, const float* __restrict__ cawk,
                         const float* __restrict__ cawv, const float* __restrict__ cawo,
                         const float* __restrict__ cabv, const float* __restrict__ cabo,
                         float* __restrict__ w0T, float* __restrict__ w1T,
                         float* __restrict__ w2T, float* __restrict__ ff2T,
                         float* __restrict__ M2sa, float* __restrict__ M2ca,
                         float* __restrict__ PMsa, float* __restrict__ PMca,
                         float* __restrict__ csa, float* __restrict__ cca){
  int stride = gridDim.x*blockDim.x;
  int tid = blockIdx.x*blockDim.x + threadIdx.x;
  for (int i=tid;i<1344;i+=stride){ int o=i&63, r=i>>6; int c=r/7, kh=r%7; w0T[i]=c0w[o*21+c*7+kh]; }
  for (int i=tid;i<12288;i+=stride){ int o=i&63, r=i>>6; int c=r>>6, rem=r&63, kh=rem>>5, kw=rem&31;
                                     w1T[i]=c1w[o*192+c*64+kh*32+kw]; }
  for (int i=tid;i<9216;i+=stride){ int o=i&63, r=i>>6; int c=r/48, kw=r%48; w2T[i]=c2w[o*144+c*48+kw]; }
  for (int i=tid;i<8192;i+=stride){ int o=i&63, j=i>>6; ff2T[i]=ff2[o*128+j]; }
  for (int i=tid;i<4096;i+=stride){
    int a=i>>6, b=i&63;
    float s1=0.f,s2=0.f,s3=0.f,s4=0.f;
    for (int o=0;o<64;o++){
      s1 = fmaf(sawk[o*64+a], sawq[o*64+b], s1);
      s2 = fmaf(cawk[o*64+a], cawq[o*64+b], s2);
      s3 = fmaf(sawo[b*64+o], sawv[o*64+a], s3);
      s4 = fmaf(cawo[b*64+o], cawv[o*64+a], s4);
    }
    M2sa[i]=s1; M2ca[i]=s2; PMsa[i]=s3; PMca[i]=s4;
  }
  for (int i=tid;i<64;i+=stride){
    float s1=sabo[i], s2=cabo[i];
    for (int d=0;d<64;d++){ s1=fmaf(sabv[d], sawo[i*64+d], s1); s2=fmaf(cabv[d], cawo[i*64+d], s2); }
    csa[i]=s1; cca[i]=s2;
  }
}

// ---------------- conv stems: x = day_seq viewed as [b][c][h(7)][w(144)] ----------------
__global__ __launch_bounds__(256) void af_conv1(const float* __restrict__ ds, const float* __restrict__ w0T,
                          const float* __restrict__ b0, float* __restrict__ out){
  int b = blockIdx.x;
  int wv = threadIdx.x>>6, lane = threadIdx.x&63;
  const float* xb = ds + (size_t)b*3024;
  for (int it=0; it<2; it++){
    int tl = it*64+lane; bool ok = tl<108;
    int t = wv*108 + (ok?tl:0);
    int h = t/144, w = t - h*144;
    for (int oc=0; oc<4; oc++){
      float acc[16];
      #pragma unroll
      for (int u=0;u<16;u++) acc[u]=b0[oc*16+u];
      for (int kh=0; kh<7; kh++){
        int hh = h+kh-1;
        bool val = (hh>=0)&&(hh<7);
        int hc = val?hh:0;
        #pragma unroll
        for (int c=0;c<3;c++){
          float xv = xb[hc*432 + w*3 + c];
          xv = val?xv:0.f;
          const float* wr = w0T + (c*7+kh)*64 + oc*16;
          #pragma unroll
          for (int u=0;u<16;u++) acc[u]=fmaf(xv,wr[u],acc[u]);
        }
      }
      if (ok){
        float* op = out + ((size_t)b*L + t)*DM + oc*16;
        #pragma unroll
        for (int q=0;q<4;q++)
          *reinterpret_cast<float4*>(op+q*4)=make_float4(acc[q*4],acc[q*4+1],acc[q*4+2],acc[q*4+3]);
      }
    }
  }
}

__global__ __launch_bounds__(256) void af_conv2(const float* __restrict__ ds, const float* __restrict__ w1T,
                          const float* __restrict__ b1, float* __restrict__ out){
  int b = blockIdx.x;
  int wv = threadIdx.x>>6, lane = threadIdx.x&63;
  const float* xb = ds + (size_t)b*3024;
  for (int it=0; it<2; it++){
    int tl = it*64+lane; bool ok = tl<108;
    int t = wv*108 + (ok?tl:0);
    int f = t + 224;           // 8*82=656 outputs, keep last 432
    int h = f/82, w = f - h*82;
    for (int oc=0; oc<4; oc++){
      float acc[16];
      #pragma unroll
      for (int u=0;u<16;u++) acc[u]=b1[oc*16+u];
      #pragma unroll
      for (int kh=0; kh<2; kh++){
        int hh = h+kh-1;       // h in [2,7] -> hh in [1,7]
        bool val = hh<7;
        int hc = val?hh:0;
        for (int kw=0; kw<32; kw++){
          #pragma unroll
          for (int c=0;c<3;c++){
            float xv = xb[hc*432 + (w+2*kw)*3 + c];
            xv = val?xv:0.f;
            const float* wr = w1T + ((c*2+kh)*32+kw)*64 + oc*16;
            #pragma unroll
            for (int u=0;u<16;u++) acc[u]=fmaf(xv,wr[u],acc[u]);
          }
        }
      }
      if (ok){
        float* op = out + ((size_t)b*L + t)*DM + oc*16;
        #pragma unroll
        for (int q=0;q<4;q++)
          *reinterpret_cast<float4*>(op+q*4)=make_float4(acc[q*4],acc[q*4+1],acc[q*4+2],acc[q*4+3]);
      }
    }
  }
}

// conv3 (trend stem): only sum_d s3[t,d]*pw[d] for t in [288,432) is ever used.
__global__ __launch_bounds__(256) void af_conv3td(const float* __restrict__ ds, const float* __restrict__ w2T,
                          const float* __restrict__ b2, const float* __restrict__ pw,
                          float* __restrict__ td){
  int b = blockIdx.x;
  int tid = threadIdx.x;
  if (tid>=144) return;
  const float* xb = ds + (size_t)b*3024;
  int t = 288+tid;
  int f = t + 247;             // 7*97=679 outputs, keep last 432
  int h = f/97, w = f - h*97;  // h in [5,6], always valid
  float tdv=0.f;
  for (int oc=0; oc<4; oc++){
    float acc[16];
    #pragma unroll
    for (int u=0;u<16;u++) acc[u]=b2[oc*16+u];
    for (int kw=0; kw<48; kw++){
      #pragma unroll
      for (int c=0;c<3;c++){
        float xv = xb[h*432 + (w+kw)*3 + c];
        const float* wr = w2T + (c*48+kw)*64 + oc*16;
        #pragma unroll
        for (int u=0;u<16;u++) acc[u]=fmaf(xv,wr[u],acc[u]);
      }
    }
    #pragma unroll
    for (int u=0;u<16;u++) tdv = fmaf(acc[u], pw[oc*16+u], tdv);
  }
  td[b*144 + tid] = tdv;
}

// ---------------- u = src @ M2 (64x64, row-major [a][b]) ----------------
__global__ __launch_bounds__(256) void af_lin(const float* __restrict__ src,
      const float* __restrict__ M2, float* __restrict__ dst){
  int b = blockIdx.y;
  int t = blockIdx.x*256 + threadIdx.x;
  if (t>=L) return;
  float xr[64];
  const float4* xp = reinterpret_cast<const float4*>(src + ((size_t)b*L+t)*DM);
  #pragma unroll
  for (int i=0;i<16;i++){ float4 v=xp[i]; xr[4*i]=v.x; xr[4*i+1]=v.y; xr[4*i+2]=v.z; xr[4*i+3]=v.w; }
  float acc[64];
  #pragma unroll
  for (int o=0;o<64;o++) acc[o]=0.f;
  for (int a=0;a<64;a++){
    float x = xr[a];
    const float* mr = M2 + a*64;
    #pragma unroll
    for (int o=0;o<64;o++) acc[o]=fmaf(x, mr[o], acc[o]);
  }
  float* orow = dst + ((size_t)b*L+t)*DM;
  #pragma unroll
  for (int q=0;q<16;q++)
    *reinterpret_cast<float4*>(orow+q*4)=make_float4(acc[q*4],acc[q*4+1],acc[q*4+2],acc[q*4+3]);
}

// ---------------- circular correlation (LDS-staged, d-half split) ----------------
// mvp[(dh*NB+b)*L + tau] = sum_t X[b,t,d-half].Y[b,(t+tau)%L,d-half]   (raw, no /64)
// Y half staged in LDS with XOR slot swizzle: slot' = slot ^ ((row>>3)&7) -> even bank
// coverage for the per-lane rolled b128 gathers (lanes' rows differ by 8).
__global__ __launch_bounds__(256) void af_corr2(const float* __restrict__ X, const float* __restrict__ Y,
                                                float* __restrict__ mvp){
  int b = blockIdx.x, dh = blockIdx.y;
  int tid = threadIdx.x;
  int wv = tid>>6, lane = tid&63;
  __shared__ float Ylds[L*32];
  __shared__ float red[4][L];
  const float* Xb = X + (size_t)b*L*DM + dh*32;
  const float* Yb = Y + (size_t)b*L*DM + dh*32;
  // stage Y half: 432 rows x 8 float4 slots, swizzled
  for (int idx=tid; idx<L*8; idx+=256){
    int row = idx>>3, slot = idx&7;
    float4 v = *reinterpret_cast<const float4*>(Yb + row*DM + slot*4);
    int s2 = slot ^ ((row>>3)&7);
    *reinterpret_cast<float4*>(&Ylds[row*32 + s2*4]) = v;
  }
  __syncthreads();
  int tau0 = lane*8;
  bool act = lane < 54;           // 54*8 = 432 taus
  float acc[8];
  #pragma unroll
  for (int a=0;a<8;a++) acc[a]=0.f;
  for (int dq=0; dq<2; dq++){
    int sl = wv*2 + dq;           // float4 slot within the 32-dim half
    const float* Xcol = Xb + sl*4;
    for (int t0=0; t0<L; t0+=16){
      float4 xq[16];
      #pragma unroll
      for (int i=0;i<16;i++)
        xq[i] = *reinterpret_cast<const float4*>(Xcol + (t0+i)*DM);  // wave-uniform
      float4 kr[8];
      #pragma unroll
      for (int j=0;j<7;j++){
        int r = t0 + tau0 + j; if (r>=L) r-=L; if(!act) r=0;
        kr[j] = *reinterpret_cast<const float4*>(&Ylds[r*32 + ((sl ^ ((r>>3)&7))<<2)]);
      }
      #pragma unroll
      for (int i=0;i<16;i++){
        int r = t0 + tau0 + i + 7; if (r>=L) r-=L; if(!act) r=0;
        kr[(i+7)&7] = *reinterpret_cast<const float4*>(&Ylds[r*32 + ((sl ^ ((r>>3)&7))<<2)]);
        float4 xv = xq[i];
        #pragma unroll
        for (int a=0;a<8;a++){
          float4 kv = kr[(i+a)&7];
          acc[a]=fmaf(xv.x,kv.x,acc[a]); acc[a]=fmaf(xv.y,kv.y,acc[a]);
          acc[a]=fmaf(xv.z,kv.z,acc[a]); acc[a]=fmaf(xv.w,kv.w,acc[a]);
        }
      }
    }
  }
  if (act){
    #pragma unroll
    for (int a=0;a<8;a++) red[wv][tau0+a]=acc[a];
  }
  __syncthreads();
  for (int t=tid; t<L; t+=256){
    float s = (red[0][t]+red[1][t]) + (red[2][t]+red[3][t]);
    mvp[((size_t)dh*NB + b)*L + t] = s;   // raw partial (no /64)
  }
}

// ---------------- batch-mean + top-4 lag selection (sums both d-halves) ----------------
__global__ void af_topk(const float* __restrict__ mvp, int* __restrict__ idx){
  __shared__ float gm[L];
  int tid = threadIdx.x;
  for (int t=tid; t<L; t+=256){
    float s=0.f;
    for (int r=0; r<2*NB; r++) s += mvp[(size_t)r*L + t];
    gm[t]=s;
  }
  __syncthreads();
  if (tid==0){
    for (int p=0;p<4;p++){
      float best=-1e30f; int bi=0;
      for (int t=0;t<L;t++){ float v=gm[t]; if (v>best){best=v;bi=t;} }
      idx[p]=bi; gm[bi]=-1e30f;
    }
  }
}

// ---------------- out[t] = resid[t] + (sum_k w_k * vsrc[(t+idx_k)%L]) @ PM + cvec ----------------
__global__ __launch_bounds__(256) void af_agg2(const float* __restrict__ vsrc, const float* __restrict__ resid,
      const float* __restrict__ mvp, const int* __restrict__ idx, const float* __restrict__ PM,
      const float* __restrict__ cvec, float* __restrict__ outp){
  int b = blockIdx.y;
  int t = blockIdx.x*256 + threadIdx.x;
  if (t>=L) return;
  int i0=idx[0],i1=idx[1],i2=idx[2],i3=idx[3];
  const float* p0 = mvp + (size_t)b*L;
  const float* p1 = mvp + ((size_t)NB + b)*L;
  float w0=(p0[i0]+p1[i0])*(1.f/64.f), w1=(p0[i1]+p1[i1])*(1.f/64.f);
  float w2=(p0[i2]+p1[i2])*(1.f/64.f), w3=(p0[i3]+p1[i3])*(1.f/64.f);
  float m = fmaxf(fmaxf(w0,w1),fmaxf(w2,w3));
  w0=expf(w0-m); w1=expf(w1-m); w2=expf(w2-m); w3=expf(w3-m);
  float inv = 1.f/(w0+w1+w2+w3);
  w0*=inv; w1*=inv; w2*=inv; w3*=inv;
  float aggx[64];
  #pragma unroll
  for (int d=0;d<64;d++) aggx[d]=0.f;
  int rr[4]={t+i0,t+i1,t+i2,t+i3};
  float ww[4]={w0,w1,w2,w3};
  #pragma unroll
  for (int k=0;k<4;k++){
    int r=rr[k]; if (r>=L) r-=L;
    const float4* vp = reinterpret_cast<const float4*>(vsrc + ((size_t)b*L+r)*DM);
    float wk=ww[k];
    #pragma unroll
    for (int i=0;i<16;i++){
      float4 q=vp[i];
      aggx[4*i]  =fmaf(wk,q.x,aggx[4*i]);   aggx[4*i+1]=fmaf(wk,q.y,aggx[4*i+1]);
      aggx[4*i+2]=fmaf(wk,q.z,aggx[4*i+2]); aggx[4*i+3]=fmaf(wk,q.w,aggx[4*i+3]);
    }
  }
  float acc[64];
  #pragma unroll
  for (int o=0;o<64;o++) acc[o]=cvec[o];
  for (int a=0;a<64;a++){
    float x = aggx[a];
    const float* pr = PM + a*64;
    #pragma unroll
    for (int o=0;o<64;o++) acc[o]=fmaf(x, pr[o], acc[o]);
  }
  const float* rrow = resid + ((size_t)b*L+t)*DM;
  float* orow = outp + ((size_t)b*L+t)*DM;
  #pragma unroll
  for (int q=0;q<16;q++){
    float4 rv = *reinterpret_cast<const float4*>(rrow+q*4);
    *reinterpret_cast<float4*>(orow+q*4)=make_float4(rv.x+acc[q*4],rv.y+acc[q*4+1],
                                                     rv.z+acc[q*4+2],rv.w+acc[q*4+3]);
  }
}

// ---------------- series_decomp: xo = x - ma25(x); ts (+)= ma25(x) for rows {0,287..431} only ----------------
__global__ void af_decomp2(const float* __restrict__ x, float* __restrict__ xo,
                           float* __restrict__ ts, int accum){
  int g = blockIdx.x*256 + threadIdx.x;
  int b = g>>8, chunk=(g>>6)&3, d=g&63;
  const float* xb = x + (size_t)b*L*DM + d;
  float* tsb = ts + (size_t)b*TSSTR + d;
  int t0 = chunk*108;
  float s = 0.f;
  for (int j=t0-12; j<=t0+12; j++){
    int jc = j<0?0:(j>L-1?L-1:j);
    s += xb[jc*DM];
  }
  for (int t=t0; t<t0+108; t++){
    float mean = s*(1.f/25.f);
    xo[(size_t)b*L*DM + t*DM + d] = xb[t*DM] - mean;
    int ridx = (t>=287) ? (t-287) : (t==0 ? 145 : -1);
    if (ridx>=0){
      float* tp = tsb + ridx*64;
      *tp = accum ? (*tp + mean) : mean;
    }
    int ja=t+13; ja = ja>L-1?L-1:ja;
    int jr=t-12; jr = jr<0?0:jr;
    s += xb[ja*DM] - xb[jr*DM];
  }
}

// ---------------- FFN: out = x + gelu(x@ff1.T)@ff2.T ----------------
__global__ __launch_bounds__(256) void af_ff(const float* __restrict__ x, const float* __restrict__ ff1,
      const float* __restrict__ ff2T, float* __restrict__ out){
  int b=blockIdx.y; int t=blockIdx.x*256+threadIdx.x;
  if (t>=L) return;
  float xr[64];
  const float4* xp = reinterpret_cast<const float4*>(x + ((size_t)b*L+t)*DM);
  #pragma unroll
  for (int i=0;i<16;i++){ float4 v=xp[i]; xr[4*i]=v.x; xr[4*i+1]=v.y; xr[4*i+2]=v.z; xr[4*i+3]=v.w; }
  float acc[64];
  #pragma unroll
  for (int o=0;o<64;o++) acc[o]=0.f;
  for (int j=0;j<128;j++){
    const float* w1r = ff1 + j*64;
    float h=0.f;
    #pragma unroll
    for (int d=0;d<64;d++) h=fmaf(xr[d],w1r[d],h);
    h = 0.5f*h*(1.f + erff(h*0.70710678118654752440f));
    const float* w2r = ff2T + j*64;
    #pragma unroll
    for (int o=0;o<64;o++) acc[o]=fmaf(h,w2r[o],acc[o]);
  }
  float* orow = out + ((size_t)b*L+t)*DM;
  #pragma unroll
  for (int q=0;q<16;q++)
    *reinterpret_cast<float4*>(orow+q*4)=make_float4(xr[q*4]+acc[q*4],xr[q*4+1]+acc[q*4+1],
                                                     xr[q*4+2]+acc[q*4+2],xr[q*4+3]+acc[q*4+3]);
}

// ---------------- final: layernorm (+ time-mean fold) + trend scalars + circ-conv trend head ----------------
__global__ __launch_bounds__(256) void af_final2(const float* __restrict__ xd, const float* __restrict__ td,
    const float* __restrict__ ts, const float* __restrict__ lng, const float* __restrict__ lnb,
    const float* __restrict__ projw, const float* __restrict__ pw, const float* __restrict__ pb,
    float* __restrict__ outp){
  int b = blockIdx.x; int tid = threadIdx.x;
  __shared__ float sv[L];
  __shared__ float cshared;
  for (int l=tid; l<L; l+=256){
    const float4* xp = reinterpret_cast<const float4*>(xd + ((size_t)b*L+l)*DM);
    float xr[64];
    #pragma unroll
    for (int i=0;i<16;i++){ float4 q=xp[i]; xr[4*i]=q.x; xr[4*i+1]=q.y; xr[4*i+2]=q.z; xr[4*i+3]=q.w; }
    float mu=0.f;
    #pragma unroll
    for (int d=0;d<64;d++) mu+=xr[d];
    mu *= (1.f/64.f);
    float var=0.f;
    #pragma unroll
    for (int d=0;d<64;d++){ float df=xr[d]-mu; var=fmaf(df,df,var); }
    var *= (1.f/64.f);
    float inv = 1.f/sqrtf(var+1e-5f);
    float s=0.f;
    #pragma unroll
    for (int d=0;d<64;d++) s += ((xr[d]-mu)*inv*lng[d] + lnb[d]) * pw[d];
    sv[l]=s;
  }
  __syncthreads();
  if (tid==0){
    float c=0.f;
    for (int l=0;l<L;l++) c+=sv[l];
    cshared = c*(1.f/432.f);
  }
  __syncthreads();
  float cv = cshared;
  int l = 288 + tid;
  if (l < L){
    const float* r0 = ts + (size_t)b*TSSTR + (l-288)*64;            // row l-1
    const float* r1 = r0 + 64;                                      // row l
    const float* r2 = (l==L-1) ? (ts + (size_t)b*TSSTR + 145*64)    // row 0 (wrap)
                               : (r1 + 64);                         // row l+1
    float rt=0.f;
    #pragma unroll
    for (int d=0;d<64;d++)
      rt += r0[d]*projw[d*3] + r1[d]*projw[d*3+1] + r2[d]*projw[d*3+2];
    float Ps=0.f;
    #pragma unroll
    for (int d=0;d<64;d++) Ps += pw[d];
    outp[b*144 + (l-288)] = sv[l] - cv + td[b*144 + (l-288)] + rt*Ps + pb[0];
  }
}

extern "C" void kernel_launch(void* const* d_in, const int* in_sizes, int n_in,
                              void* d_out, int out_size, void* d_ws, size_t ws_size,
                              hipStream_t stream) {
  const float* day  = (const float*)d_in[0];
  const float* c0w  = (const float*)d_in[1];
  const float* c0b  = (const float*)d_in[2];
  const float* c1w  = (const float*)d_in[3];
  const float* c1b  = (const float*)d_in[4];
  const float* c2w  = (const float*)d_in[5];
  const float* c2b  = (const float*)d_in[6];
  const float* sa_wq=(const float*)d_in[7];  const float* sa_bq=(const float*)d_in[8];
  const float* sa_wk=(const float*)d_in[9];  const float* sa_bk=(const float*)d_in[10];
  const float* sa_wv=(const float*)d_in[11]; const float* sa_bv=(const float*)d_in[12];
  const float* sa_wo=(const float*)d_in[13]; const float* sa_bo=(const float*)d_in[14];
  const float* ca_wq=(const float*)d_in[15]; const float* ca_bq=(const float*)d_in[16];
  const float* ca_wk=(const float*)d_in[17]; const float* ca_bk=(const float*)d_in[18];
  const float* ca_wv=(const float*)d_in[19]; const float* ca_bv=(const float*)d_in[20];
  const float* ca_wo=(const float*)d_in[21]; const float* ca_bo=(const float*)d_in[22];
  const float* ff1w = (const float*)d_in[23];
  const float* ff2w = (const float*)d_in[24];
  const float* projw= (const float*)d_in[25];
  const float* lng  = (const float*)d_in[26];
  const float* lnb  = (const float*)d_in[27];
  const float* predw= (const float*)d_in[28];
  const float* predb= (const float*)d_in[29];
  (void)sa_bq; (void)sa_bk; (void)ca_bq; (void)ca_bk;  // provably cancel in softmax/top-k
  float* out = (float*)d_out;

  const size_t SZ = (size_t)NB*L*DM;          // 14,155,776 floats per panel
  const size_t need = 3*SZ + (size_t)NB*TSSTR + (size_t)NB*144 + 2*(size_t)NB*L + 16
                      + 1344 + 12288 + 9216 + 8192 + 4*4096 + 128;
  if (ws_size < need*sizeof(float)){
    af_wsdiag<<<dim3(1), dim3(64), 0, stream>>>(out, (float)(ws_size>>20));
    return;
  }

  float* ws = (float*)d_ws;
  float* A  = ws;
  float* B  = A + SZ;
  float* C  = B + SZ;
  float* TS = C + SZ;                         // NB*146*64
  float* TD = TS + (size_t)NB*TSSTR;          // NB*144
  float* MVP= TD + (size_t)NB*144;            // 2*NB*L (two d-half partials)
  int*   IDXP = (int*)(MVP + 2*(size_t)NB*L);
  float* WT = MVP + 2*(size_t)NB*L + 16;
  float* w0T = WT;             // 1344
  float* w1T = w0T + 1344;     // 12288
  float* w2T = w1T + 12288;    // 9216
  float* ff2T= w2T + 9216;     // 8192
  float* M2sa= ff2T + 8192;    // 4096
  float* M2ca= M2sa + 4096;
  float* PMsa= M2ca + 4096;
  float* PMca= PMsa + 4096;
  float* csa = PMca + 4096;    // 64
  float* cca = csa + 64;       // 64

  dim3 blk(256);
  dim3 gridT(2, NB);
  dim3 gridC(NB, 2);

  af_wprep<<<dim3(48), blk, 0, stream>>>(c0w, c1w, c2w, ff2w,
      sa_wq, sa_wk, sa_wv, sa_wo, sa_bv, sa_bo,
      ca_wq, ca_wk, ca_wv, ca_wo, ca_bv, ca_bo,
      w0T, w1T, w2T, ff2T, M2sa, M2ca, PMsa, PMca, csa, cca);
  af_conv1 <<<dim3(NB), blk, 0, stream>>>(day, w0T, c0b, A);          // A = xd0
  af_conv2 <<<dim3(NB), blk, 0, stream>>>(day, w1T, c1b, B);          // B = cross
  af_conv3td<<<dim3(NB), blk, 0, stream>>>(day, w2T, c2b, predw, TD); // TD = trend . pw

  // ---- self attention ----
  af_lin  <<<gridT, blk, 0, stream>>>(A, M2sa, C);                    // C = u
  af_corr2<<<gridC, blk, 0, stream>>>(C, A, MVP);
  af_topk <<<dim3(1), blk, 0, stream>>>(MVP, IDXP);
  af_agg2 <<<gridT, blk, 0, stream>>>(A, A, MVP, IDXP, PMsa, csa, C); // C = xd1
  af_decomp2<<<dim3(NB), blk, 0, stream>>>(C, A, TS, 0);              // A = xd2, TS = t1

  // ---- cross attention ----
  af_lin  <<<gridT, blk, 0, stream>>>(B, M2ca, C);                    // C = u (from cross)
  af_corr2<<<gridC, blk, 0, stream>>>(C, A, MVP);
  af_topk <<<dim3(1), blk, 0, stream>>>(MVP, IDXP);
  af_agg2 <<<gridT, blk, 0, stream>>>(B, A, MVP, IDXP, PMca, cca, C); // C = xd3 (v from cross)
  af_decomp2<<<dim3(NB), blk, 0, stream>>>(C, A, TS, 1);              // A = xd4, TS += t2

  // ---- FFN ----
  af_ff<<<gridT, blk, 0, stream>>>(A, ff1w, ff2T, B);                 // B = xd4 + ffn
  af_decomp2<<<dim3(NB), blk, 0, stream>>>(B, A, TS, 1);              // A = xd5, TS += t3

  // ---- layernorm + trend + head ----
  af_final2<<<dim3(NB), blk, 0, stream>>>(A, TD, TS, lng, lnb, projw, predw, predb, out);
}

// Round 10
// 1857.711 us; speedup vs baseline: 2.8364x; 1.0783x over previous
//
#include <hip/hip_runtime.h>

#define L 432
#define DM 64
#define NB 512
#define TSROWS 146   // rows {287..431} -> 0..144, row 0 -> 145
#define TSSTR  (TSROWS*DM)
#define NROWS (NB*L) // 221184 = 864*256

// ---------------- diagnostic: encode ws_size (MB) into absmax if workspace too small ----------------
__global__ void af_wsdiag(float* __restrict__ out, float val){
  if (threadIdx.x==0) out[0]=val;
}

// ---------------- weight prep: conv transposes, ff2T, fused attn matrices ----------------
__global__ void af_wprep(const float* __restrict__ c0w, const float* __restrict__ c1w,
                         const float* __restrict__ c2w, const float* __restrict__ ff2,
                         const float* __restrict__ sawq, const float* __restrict__ sawk,
                         const float* __restrict__ sawv, const float* __restrict__ sawo,
                         const float* __restrict__ sabv, const float* __restrict__ sabo,
                         const float* __restrict__ cawq, const float* __restrict__ cawk,
                         const float* __restrict__ cawv, const float* __restrict__ cawo,
                         const float* __restrict__ cabv, const float* __restrict__ cabo,
                         float* __restrict__ w0T, float* __restrict__ w1T,
                         float* __restrict__ w2T, float* __restrict__ ff2T,
                         float* __restrict__ M2sa, float* __restrict__ M2ca,
                         float* __restrict__ PMsa, float* __restrict__ PMca,
                         float* __restrict__ csa, float* __restrict__ cca){
  int stride = gridDim.x*blockDim.x;
  int tid = blockIdx.x*blockDim.x + threadIdx.x;
  for (int i=tid;i<1344;i+=stride){ int o=i&63, r=i>>6; int c=r/7, kh=r%7; w0T[i]=c0w[o*21+c*7+kh]; }
  for (int i=tid;i<12288;i+=stride){ int o=i&63, r=i>>6; int c=r>>6, rem=r&63, kh=rem>>5, kw=rem&31;
                                     w1T[i]=c1w[o*192+c*64+kh*32+kw]; }
  for (int i=tid;i<9216;i+=stride){ int o=i&63, r=i>>6; int c=r/48, kw=r%48; w2T[i]=c2w[o*144+c*48+kw]; }
  for (int i=tid;i<8192;i+=stride){ int o=i&63, j=i>>6; ff2T[i]=ff2[o*128+j]; }
  for (int i=tid;i<4096;i+=stride){
    int a=i>>6, b=i&63;
    float s1=0.f,s2=0.f,s3=0.f,s4=0.f;
    for (int o=0;o<64;o++){
      s1 = fmaf(sawk[o*64+a], sawq[o*64+b], s1);
      s2 = fmaf(cawk[o*64+a], cawq[o*64+b], s2);
      s3 = fmaf(sawo[b*64+o], sawv[o*64+a], s3);
      s4 = fmaf(cawo[b*64+o], cawv[o*64+a], s4);
    }
    M2sa[i]=s1; M2ca[i]=s2; PMsa[i]=s3; PMca[i]=s4;
  }
  for (int i=tid;i<64;i+=stride){
    float s1=sabo[i], s2=cabo[i];
    for (int d=0;d<64;d++){ s1=fmaf(sabv[d], sawo[i*64+d], s1); s2=fmaf(cabv[d], cawo[i*64+d], s2); }
    csa[i]=s1; cca[i]=s2;
  }
}

// ---------------- conv stems: x = day_seq viewed as [b][c][h(7)][w(144)] ----------------
__global__ __launch_bounds__(256) void af_conv1(const float* __restrict__ ds, const float* __restrict__ w0T,
                          const float* __restrict__ b0, float* __restrict__ out){
  int b = blockIdx.x;
  int wv = threadIdx.x>>6, lane = threadIdx.x&63;
  const float* xb = ds + (size_t)b*3024;
  for (int it=0; it<2; it++){
    int tl = it*64+lane; bool ok = tl<108;
    int t = wv*108 + (ok?tl:0);
    int h = t/144, w = t - h*144;
    for (int oc=0; oc<4; oc++){
      float acc[16];
      #pragma unroll
      for (int u=0;u<16;u++) acc[u]=b0[oc*16+u];
      for (int kh=0; kh<7; kh++){
        int hh = h+kh-1;
        bool val = (hh>=0)&&(hh<7);
        int hc = val?hh:0;
        #pragma unroll
        for (int c=0;c<3;c++){
          float xv = xb[hc*432 + w*3 + c];
          xv = val?xv:0.f;
          const float* wr = w0T + (c*7+kh)*64 + oc*16;
          #pragma unroll
          for (int u=0;u<16;u++) acc[u]=fmaf(xv,wr[u],acc[u]);
        }
      }
      if (ok){
        float* op = out + ((size_t)b*L + t)*DM + oc*16;
        #pragma unroll
        for (int q=0;q<4;q++)
          *reinterpret_cast<float4*>(op+q*4)=make_float4(acc[q*4],acc[q*4+1],acc[q*4+2],acc[q*4+3]);
      }
    }
  }
}

__global__ __launch_bounds__(256) void af_conv2(const float* __restrict__ ds, const float* __restrict__ w1T,
                          const float* __restrict__ b1, float* __restrict__ out){
  int b = blockIdx.x;
  int wv = threadIdx.x>>6, lane = threadIdx.x&63;
  const float* xb = ds + (size_t)b*3024;
  for (int it=0; it<2; it++){
    int tl = it*64+lane; bool ok = tl<108;
    int t = wv*108 + (ok?tl:0);
    int f = t + 224;           // 8*82=656 outputs, keep last 432
    int h = f/82, w = f - h*82;
    for (int oc=0; oc<4; oc++){
      float acc[16];
      #pragma unroll
      for (int u=0;u<16;u++) acc[u]=b1[oc*16+u];
      #pragma unroll
      for (int kh=0; kh<2; kh++){
        int hh = h+kh-1;       // h in [2,7] -> hh in [1,7]
        bool val = hh<7;
        int hc = val?hh:0;
        for (int kw=0; kw<32; kw++){
          #pragma unroll
          for (int c=0;c<3;c++){
            float xv = xb[hc*432 + (w+2*kw)*3 + c];
            xv = val?xv:0.f;
            const float* wr = w1T + ((c*2+kh)*32+kw)*64 + oc*16;
            #pragma unroll
            for (int u=0;u<16;u++) acc[u]=fmaf(xv,wr[u],acc[u]);
          }
        }
      }
      if (ok){
        float* op = out + ((size_t)b*L + t)*DM + oc*16;
        #pragma unroll
        for (int q=0;q<4;q++)
          *reinterpret_cast<float4*>(op+q*4)=make_float4(acc[q*4],acc[q*4+1],acc[q*4+2],acc[q*4+3]);
      }
    }
  }
}

// conv3 (trend stem): only sum_d s3[t,d]*pw[d] for t in [288,432) is ever used.
__global__ __launch_bounds__(256) void af_conv3td(const float* __restrict__ ds, const float* __restrict__ w2T,
                          const float* __restrict__ b2, const float* __restrict__ pw,
                          float* __restrict__ td){
  int b = blockIdx.x;
  int tid = threadIdx.x;
  if (tid>=144) return;
  const float* xb = ds + (size_t)b*3024;
  int t = 288+tid;
  int f = t + 247;             // 7*97=679 outputs, keep last 432
  int h = f/97, w = f - h*97;  // h in [5,6], always valid
  float tdv=0.f;
  for (int oc=0; oc<4; oc++){
    float acc[16];
    #pragma unroll
    for (int u=0;u<16;u++) acc[u]=b2[oc*16+u];
    for (int kw=0; kw<48; kw++){
      #pragma unroll
      for (int c=0;c<3;c++){
        float xv = xb[h*432 + (w+kw)*3 + c];
        const float* wr = w2T + (c*48+kw)*64 + oc*16;
        #pragma unroll
        for (int u=0;u<16;u++) acc[u]=fmaf(xv,wr[u],acc[u]);
      }
    }
    #pragma unroll
    for (int u=0;u<16;u++) tdv = fmaf(acc[u], pw[oc*16+u], tdv);
  }
  td[b*144 + tid] = tdv;
}

// ---------------- u = src @ M2 (64x64, row-major [a][b]); flattened row-per-thread ----------------
__global__ __launch_bounds__(256) void af_lin(const float* __restrict__ src,
      const float* __restrict__ M2, float* __restrict__ dst){
  size_t row = (size_t)blockIdx.x*256 + threadIdx.x;   // < NROWS exactly
  float xr[64];
  const float4* xp = reinterpret_cast<const float4*>(src + row*DM);
  #pragma unroll
  for (int i=0;i<16;i++){ float4 v=xp[i]; xr[4*i]=v.x; xr[4*i+1]=v.y; xr[4*i+2]=v.z; xr[4*i+3]=v.w; }
  float acc[64];
  #pragma unroll
  for (int o=0;o<64;o++) acc[o]=0.f;
  for (int a=0;a<64;a++){
    float x = xr[a];
    const float* mr = M2 + a*64;
    #pragma unroll
    for (int o=0;o<64;o++) acc[o]=fmaf(x, mr[o], acc[o]);
  }
  float* orow = dst + row*DM;
  #pragma unroll
  for (int q=0;q<16;q++)
    *reinterpret_cast<float4*>(orow+q*4)=make_float4(acc[q*4],acc[q*4+1],acc[q*4+2],acc[q*4+3]);
}

// ---------------- circular correlation (LDS-staged, d-half split) ----------------
// mvp[(dh*NB+b)*L + tau] = sum_t X[b,t,d-half].Y[b,(t+tau)%L,d-half]   (raw, no /64)
__global__ __launch_bounds__(256) void af_corr2(const float* __restrict__ X, const float* __restrict__ Y,
                                                float* __restrict__ mvp){
  int b = blockIdx.x, dh = blockIdx.y;
  int tid = threadIdx.x;
  int wv = tid>>6, lane = tid&63;
  __shared__ float Ylds[L*32];
  __shared__ float red[4][L];
  const float* Xb = X + (size_t)b*L*DM + dh*32;
  const float* Yb = Y + (size_t)b*L*DM + dh*32;
  for (int idx=tid; idx<L*8; idx+=256){
    int row = idx>>3, slot = idx&7;
    float4 v = *reinterpret_cast<const float4*>(Yb + row*DM + slot*4);
    int s2 = slot ^ ((row>>3)&7);
    *reinterpret_cast<float4*>(&Ylds[row*32 + s2*4]) = v;
  }
  __syncthreads();
  int tau0 = lane*8;
  bool act = lane < 54;           // 54*8 = 432 taus
  float acc[8];
  #pragma unroll
  for (int a=0;a<8;a++) acc[a]=0.f;
  for (int dq=0; dq<2; dq++){
    int sl = wv*2 + dq;           // float4 slot within the 32-dim half
    const float* Xcol = Xb + sl*4;
    for (int t0=0; t0<L; t0+=16){
      float4 xq[16];
      #pragma unroll
      for (int i=0;i<16;i++)
        xq[i] = *reinterpret_cast<const float4*>(Xcol + (t0+i)*DM);  // wave-uniform
      float4 kr[8];
      #pragma unroll
      for (int j=0;j<7;j++){
        int r = t0 + tau0 + j; if (r>=L) r-=L; if(!act) r=0;
        kr[j] = *reinterpret_cast<const float4*>(&Ylds[r*32 + ((sl ^ ((r>>3)&7))<<2)]);
      }
      #pragma unroll
      for (int i=0;i<16;i++){
        int r = t0 + tau0 + i + 7; if (r>=L) r-=L; if(!act) r=0;
        kr[(i+7)&7] = *reinterpret_cast<const float4*>(&Ylds[r*32 + ((sl ^ ((r>>3)&7))<<2)]);
        float4 xv = xq[i];
        #pragma unroll
        for (int a=0;a<8;a++){
          float4 kv = kr[(i+a)&7];
          acc[a]=fmaf(xv.x,kv.x,acc[a]); acc[a]=fmaf(xv.y,kv.y,acc[a]);
          acc[a]=fmaf(xv.z,kv.z,acc[a]); acc[a]=fmaf(xv.w,kv.w,acc[a]);
        }
      }
    }
  }
  if (act){
    #pragma unroll
    for (int a=0;a<8;a++) red[wv][tau0+a]=acc[a];
  }
  __syncthreads();
  for (int t=tid; t<L; t+=256){
    float s = (red[0][t]+red[1][t]) + (red[2][t]+red[3][t]);
    mvp[((size_t)dh*NB + b)*L + t] = s;   // raw partial (no /64)
  }
}

// ---------------- top-4 lag selection: stage A (partial column sums over 32-row chunks) ----------------
__global__ __launch_bounds__(256) void af_topkA(const float* __restrict__ mvp, float* __restrict__ part){
  int blk = blockIdx.x;          // 0..31, rows [blk*32, blk*32+32)
  int tid = threadIdx.x;
  for (int t=tid; t<L; t+=256){
    float s=0.f;
    const float* p = mvp + (size_t)blk*32*L + t;
    for (int r=0; r<32; r++) s += p[(size_t)r*L];
    part[blk*L+t]=s;
  }
}

// ---------------- top-4 lag selection: stage B (reduce 32 partials, pick top4) ----------------
__global__ void af_topkB(const float* __restrict__ part, int* __restrict__ idx){
  __shared__ float gm[L];
  int tid = threadIdx.x;
  for (int t=tid; t<L; t+=256){
    float s=0.f;
    for (int k=0;k<32;k++) s += part[k*L+t];
    gm[t]=s;
  }
  __syncthreads();
  if (tid==0){
    for (int p=0;p<4;p++){
      float best=-1e30f; int bi=0;
      for (int t=0;t<L;t++){ float v=gm[t]; if (v>best){best=v;bi=t;} }
      idx[p]=bi; gm[bi]=-1e30f;
    }
  }
}

// ---------------- out[t] = resid[t] + (sum_k w_k * vsrc[(t+idx_k)%L]) @ PM + cvec ----------------
__global__ __launch_bounds__(256) void af_agg2(const float* __restrict__ vsrc, const float* __restrict__ resid,
      const float* __restrict__ mvp, const int* __restrict__ idx, const float* __restrict__ PM,
      const float* __restrict__ cvec, float* __restrict__ outp){
  int g = blockIdx.x*256 + threadIdx.x;    // < NROWS
  int b = g/L, t = g - b*L;
  int i0=idx[0],i1=idx[1],i2=idx[2],i3=idx[3];
  const float* p0 = mvp + (size_t)b*L;
  const float* p1 = mvp + ((size_t)NB + b)*L;
  float w0=(p0[i0]+p1[i0])*(1.f/64.f), w1=(p0[i1]+p1[i1])*(1.f/64.f);
  float w2=(p0[i2]+p1[i2])*(1.f/64.f), w3=(p0[i3]+p1[i3])*(1.f/64.f);
  float m = fmaxf(fmaxf(w0,w1),fmaxf(w2,w3));
  w0=expf(w0-m); w1=expf(w1-m); w2=expf(w2-m); w3=expf(w3-m);
  float inv = 1.f/(w0+w1+w2+w3);
  w0*=inv; w1*=inv; w2*=inv; w3*=inv;
  float aggx[64];
  #pragma unroll
  for (int d=0;d<64;d++) aggx[d]=0.f;
  int rr[4]={t+i0,t+i1,t+i2,t+i3};
  float ww[4]={w0,w1,w2,w3};
  #pragma unroll
  for (int k=0;k<4;k++){
    int r=rr[k]; if (r>=L) r-=L;
    const float4* vp = reinterpret_cast<const float4*>(vsrc + ((size_t)b*L+r)*DM);
    float wk=ww[k];
    #pragma unroll
    for (int i=0;i<16;i++){
      float4 q=vp[i];
      aggx[4*i]  =fmaf(wk,q.x,aggx[4*i]);   aggx[4*i+1]=fmaf(wk,q.y,aggx[4*i+1]);
      aggx[4*i+2]=fmaf(wk,q.z,aggx[4*i+2]); aggx[4*i+3]=fmaf(wk,q.w,aggx[4*i+3]);
    }
  }
  float acc[64];
  #pragma unroll
  for (int o=0;o<64;o++) acc[o]=cvec[o];
  for (int a=0;a<64;a++){
    float x = aggx[a];
    const float* pr = PM + a*64;
    #pragma unroll
    for (int o=0;o<64;o++) acc[o]=fmaf(x, pr[o], acc[o]);
  }
  const float* rrow = resid + (size_t)g*DM;
  float* orow = outp + (size_t)g*DM;
  #pragma unroll
  for (int q=0;q<16;q++){
    float4 rv = *reinterpret_cast<const float4*>(rrow+q*4);
    *reinterpret_cast<float4*>(orow+q*4)=make_float4(rv.x+acc[q*4],rv.y+acc[q*4+1],
                                                     rv.z+acc[q*4+2],rv.w+acc[q*4+3]);
  }
}

// ---------------- series_decomp: xo = x - ma25(x); ts (+)= ma25(x) for rows {0,287..431} only ----------------
__global__ void af_decomp2(const float* __restrict__ x, float* __restrict__ xo,
                           float* __restrict__ ts, int accum){
  int g = blockIdx.x*256 + threadIdx.x;
  int b = g>>8, chunk=(g>>6)&3, d=g&63;
  const float* xb = x + (size_t)b*L*DM + d;
  float* tsb = ts + (size_t)b*TSSTR + d;
  int t0 = chunk*108;
  float s = 0.f;
  for (int j=t0-12; j<=t0+12; j++){
    int jc = j<0?0:(j>L-1?L-1:j);
    s += xb[jc*DM];
  }
  for (int t=t0; t<t0+108; t++){
    float mean = s*(1.f/25.f);
    xo[(size_t)b*L*DM + t*DM + d] = xb[t*DM] - mean;
    int ridx = (t>=287) ? (t-287) : (t==0 ? 145 : -1);
    if (ridx>=0){
      float* tp = tsb + ridx*64;
      *tp = accum ? (*tp + mean) : mean;
    }
    int ja=t+13; ja = ja>L-1?L-1:ja;
    int jr=t-12; jr = jr<0?0:jr;
    s += xb[ja*DM] - xb[jr*DM];
  }
}

// ---------------- FFN: out = x + gelu(x@ff1.T)@ff2.T  (flattened, float4 ILP, j-unroll 2) ----------------
__global__ __launch_bounds__(256) void af_ff(const float* __restrict__ x, const float* __restrict__ ff1,
      const float* __restrict__ ff2T, float* __restrict__ out){
  size_t row = (size_t)blockIdx.x*256 + threadIdx.x;   // < NROWS exactly
  const float4* xp = reinterpret_cast<const float4*>(x + row*DM);
  float4 xq[16];
  #pragma unroll
  for (int i=0;i<16;i++) xq[i]=xp[i];
  float4 acc[16];
  #pragma unroll
  for (int o=0;o<16;o++) acc[o]=make_float4(0.f,0.f,0.f,0.f);
  for (int j=0;j<128;j+=2){
    const float4* wa = reinterpret_cast<const float4*>(ff1 + j*64);
    const float4* wb = wa + 16;
    float4 ha=make_float4(0.f,0.f,0.f,0.f), hb=ha;
    #pragma unroll
    for (int i=0;i<16;i++){
      float4 xv=xq[i], a=wa[i], b=wb[i];
      ha.x=fmaf(xv.x,a.x,ha.x); ha.y=fmaf(xv.y,a.y,ha.y);
      ha.z=fmaf(xv.z,a.z,ha.z); ha.w=fmaf(xv.w,a.w,ha.w);
      hb.x=fmaf(xv.x,b.x,hb.x); hb.y=fmaf(xv.y,b.y,hb.y);
      hb.z=fmaf(xv.z,b.z,hb.z); hb.w=fmaf(xv.w,b.w,hb.w);
    }
    float hA=(ha.x+ha.y)+(ha.z+ha.w);
    float hB=(hb.x+hb.y)+(hb.z+hb.w);
    hA = 0.5f*hA*(1.f + erff(hA*0.70710678118654752440f));
    hB = 0.5f*hB*(1.f + erff(hB*0.70710678118654752440f));
    const float4* va = reinterpret_cast<const float4*>(ff2T + j*64);
    const float4* vb = va + 16;
    #pragma unroll
    for (int o=0;o<16;o++){
      float4 w2a=va[o], w2b=vb[o], a=acc[o];
      a.x=fmaf(hA,w2a.x,a.x); a.y=fmaf(hA,w2a.y,a.y);
      a.z=fmaf(hA,w2a.z,a.z); a.w=fmaf(hA,w2a.w,a.w);
      a.x=fmaf(hB,w2b.x,a.x); a.y=fmaf(hB,w2b.y,a.y);
      a.z=fmaf(hB,w2b.z,a.z); a.w=fmaf(hB,w2b.w,a.w);
      acc[o]=a;
    }
  }
  float* orow = out + row*DM;
  #pragma unroll
  for (int q=0;q<16;q++){
    float4 xv=xq[q], a=acc[q];
    *reinterpret_cast<float4*>(orow+q*4)=make_float4(xv.x+a.x,xv.y+a.y,xv.z+a.z,xv.w+a.w);
  }
}

// ---------------- final: layernorm (+ time-mean fold) + trend scalars + circ-conv trend head ----------------
__global__ __launch_bounds__(256) void af_final2(const float* __restrict__ xd, const float* __restrict__ td,
    const float* __restrict__ ts, const float* __restrict__ lng, const float* __restrict__ lnb,
    const float* __restrict__ projw, const float* __restrict__ pw, const float* __restrict__ pb,
    float* __restrict__ outp){
  int b = blockIdx.x; int tid = threadIdx.x;
  __shared__ float sv[L];
  __shared__ float cshared;
  for (int l=tid; l<L; l+=256){
    const float4* xp = reinterpret_cast<const float4*>(xd + ((size_t)b*L+l)*DM);
    float xr[64];
    #pragma unroll
    for (int i=0;i<16;i++){ float4 q=xp[i]; xr[4*i]=q.x; xr[4*i+1]=q.y; xr[4*i+2]=q.z; xr[4*i+3]=q.w; }
    float mu=0.f;
    #pragma unroll
    for (int d=0;d<64;d++) mu+=xr[d];
    mu *= (1.f/64.f);
    float var=0.f;
    #pragma unroll
    for (int d=0;d<64;d++){ float df=xr[d]-mu; var=fmaf(df,df,var); }
    var *= (1.f/64.f);
    float inv = 1.f/sqrtf(var+1e-5f);
    float s=0.f;
    #pragma unroll
    for (int d=0;d<64;d++) s += ((xr[d]-mu)*inv*lng[d] + lnb[d]) * pw[d];
    sv[l]=s;
  }
  __syncthreads();
  if (tid==0){
    float c=0.f;
    for (int l=0;l<L;l++) c+=sv[l];
    cshared = c*(1.f/432.f);
  }
  __syncthreads();
  float cv = cshared;
  int l = 288 + tid;
  if (l < L){
    const float* r0 = ts + (size_t)b*TSSTR + (l-288)*64;            // row l-1
    const float* r1 = r0 + 64;                                      // row l
    const float* r2 = (l==L-1) ? (ts + (size_t)b*TSSTR + 145*64)    // row 0 (wrap)
                               : (r1 + 64);                         // row l+1
    float rt=0.f;
    #pragma unroll
    for (int d=0;d<64;d++)
      rt += r0[d]*projw[d*3] + r1[d]*projw[d*3+1] + r2[d]*projw[d*3+2];
    float Ps=0.f;
    #pragma unroll
    for (int d=0;d<64;d++) Ps += pw[d];
    outp[b*144 + (l-288)] = sv[l] - cv + td[b*144 + (l-288)] + rt*Ps + pb[0];
  }
}

extern "C" void kernel_launch(void* const* d_in, const int* in_sizes, int n_in,
                              void* d_out, int out_size, void* d_ws, size_t ws_size,
                              hipStream_t stream) {
  const float* day  = (const float*)d_in[0];
  const float* c0w  = (const float*)d_in[1];
  const float* c0b  = (const float*)d_in[2];
  const float* c1w  = (const float*)d_in[3];
  const float* c1b  = (const float*)d_in[4];
  const float* c2w  = (const float*)d_in[5];
  const float* c2b  = (const float*)d_in[6];
  const float* sa_wq=(const float*)d_in[7];  const float* sa_bq=(const float*)d_in[8];
  const float* sa_wk=(const float*)d_in[9];  const float* sa_bk=(const float*)d_in[10];
  const float* sa_wv=(const float*)d_in[11]; const float* sa_bv=(const float*)d_in[12];
  const float* sa_wo=(const float*)d_in[13]; const float* sa_bo=(const float*)d_in[14];
  const float* ca_wq=(const float*)d_in[15]; const float* ca_bq=(const float*)d_in[16];
  const float* ca_wk=(const float*)d_in[17]; const float* ca_bk=(const float*)d_in[18];
  const float* ca_wv=(const float*)d_in[19]; const float* ca_bv=(const float*)d_in[20];
  const float* ca_wo=(const float*)d_in[21]; const float* ca_bo=(const float*)d_in[22];
  const float* ff1w = (const float*)d_in[23];
  const float* ff2w = (const float*)d_in[24];
  const float* projw= (const float*)d_in[25];
  const float* lng  = (const float*)d_in[26];
  const float* lnb  = (const float*)d_in[27];
  const float* predw= (const float*)d_in[28];
  const float* predb= (const float*)d_in[29];
  (void)sa_bq; (void)sa_bk; (void)ca_bq; (void)ca_bk;  // provably cancel in softmax/top-k
  float* out = (float*)d_out;

  const size_t SZ = (size_t)NB*L*DM;          // 14,155,776 floats per panel
  const size_t need = 3*SZ + (size_t)NB*TSSTR + (size_t)NB*144 + 2*(size_t)NB*L + 16
                      + 1344 + 12288 + 9216 + 8192 + 4*4096 + 128 + 32*L + 64;
  if (ws_size < need*sizeof(float)){
    af_wsdiag<<<dim3(1), dim3(64), 0, stream>>>(out, (float)(ws_size>>20));
    return;
  }

  float* ws = (float*)d_ws;
  float* A  = ws;
  float* B  = A + SZ;
  float* C  = B + SZ;
  float* TS = C + SZ;                         // NB*146*64
  float* TD = TS + (size_t)NB*TSSTR;          // NB*144
  float* MVP= TD + (size_t)NB*144;            // 2*NB*L (two d-half partials)
  int*   IDXP = (int*)(MVP + 2*(size_t)NB*L);
  float* WT = MVP + 2*(size_t)NB*L + 16;
  float* w0T = WT;             // 1344
  float* w1T = w0T + 1344;     // 12288
  float* w2T = w1T + 12288;    // 9216
  float* ff2T= w2T + 9216;     // 8192
  float* M2sa= ff2T + 8192;    // 4096
  float* M2ca= M2sa + 4096;
  float* PMsa= M2ca + 4096;
  float* PMca= PMsa + 4096;
  float* csa = PMca + 4096;    // 64
  float* cca = csa + 64;       // 64
  float* TPART = cca + 64;     // 32*L partial column sums

  dim3 blk(256);
  dim3 gridR(NROWS/256);       // 864 blocks, exact
  dim3 gridC(NB, 2);

  af_wprep<<<dim3(48), blk, 0, stream>>>(c0w, c1w, c2w, ff2w,
      sa_wq, sa_wk, sa_wv, sa_wo, sa_bv, sa_bo,
      ca_wq, ca_wk, ca_wv, ca_wo, ca_bv, ca_bo,
      w0T, w1T, w2T, ff2T, M2sa, M2ca, PMsa, PMca, csa, cca);
  af_conv1 <<<dim3(NB), blk, 0, stream>>>(day, w0T, c0b, A);          // A = xd0
  af_conv2 <<<dim3(NB), blk, 0, stream>>>(day, w1T, c1b, B);          // B = cross
  af_conv3td<<<dim3(NB), blk, 0, stream>>>(day, w2T, c2b, predw, TD); // TD = trend . pw

  // ---- self attention ----
  af_lin  <<<gridR, blk, 0, stream>>>(A, M2sa, C);                    // C = u
  af_corr2<<<gridC, blk, 0, stream>>>(C, A, MVP);
  af_topkA<<<dim3(32), blk, 0, stream>>>(MVP, TPART);
  af_topkB<<<dim3(1), blk, 0, stream>>>(TPART, IDXP);
  af_agg2 <<<gridR, blk, 0, stream>>>(A, A, MVP, IDXP, PMsa, csa, C); // C = xd1
  af_decomp2<<<dim3(NB), blk, 0, stream>>>(C, A, TS, 0);              // A = xd2, TS = t1

  // ---- cross attention ----
  af_lin  <<<gridR, blk, 0, stream>>>(B, M2ca, C);                    // C = u (from cross)
  af_corr2<<<gridC, blk, 0, stream>>>(C, A, MVP);
  af_topkA<<<dim3(32), blk, 0, stream>>>(MVP, TPART);
  af_topkB<<<dim3(1), blk, 0, stream>>>(TPART, IDXP);
  af_agg2 <<<gridR, blk, 0, stream>>>(B, A, MVP, IDXP, PMca, cca, C); // C = xd3 (v from cross)
  af_decomp2<<<dim3(NB), blk, 0, stream>>>(C, A, TS, 1);              // A = xd4, TS += t2

  // ---- FFN ----
  af_ff<<<gridR, blk, 0, stream>>>(A, ff1w, ff2T, B);                 // B = xd4 + ffn
  af_decomp2<<<dim3(NB), blk, 0, stream>>>(B, A, TS, 1);              // A = xd5, TS += t3

  // ---- layernorm + trend + head ----
  af_final2<<<dim3(NB), blk, 0, stream>>>(A, TD, TS, lng, lnb, projw, predw, predb, out);
}